// Round 18
// baseline (331.977 us; speedup 1.0000x reference)
//
#include <hip/hip_runtime.h>
#include <stdint.h>
#include <float.h>

// x[4096,256] f32, keys[65536,256] f32, values[65536,10] f32, k=8 (hardcoded).
#define B_ROWS 4096
#define N_KEYS 65536
#define DDIM 256
#define NCH 10

#define NSPLIT 16
#define SPLIT_KEYS (N_KEYS / NSPLIT)       // 4096
#define ROWS_PER_BLK 128
#define CHUNK_KEYS 64
#define NCHUNK (SPLIT_KEYS / CHUNK_KEYS)   // 64
#define RECB 33792                          // 32KB keys + 256B ksq + 768B pad

typedef float f32x4 __attribute__((ext_vector_type(4)));
typedef float f32x16 __attribute__((ext_vector_type(16)));
typedef short bf16x8 __attribute__((ext_vector_type(8)));

static __device__ __forceinline__ unsigned short f2bf(float f) {
  unsigned u = __float_as_uint(f);
  return (unsigned short)((u + 0x7FFFu + ((u >> 16) & 1u)) >> 16);
}
static __device__ __forceinline__ unsigned ford(float f) {
  unsigned u = __float_as_uint(f);
  return u ^ ((unsigned)((int)u >> 31) | 0x80000000u);
}
static __device__ __forceinline__ unsigned long long shfl_xor_u64(unsigned long long v, int m) {
  unsigned lo = __shfl_xor((unsigned)v, m, 64);
  unsigned hi = __shfl_xor((unsigned)(v >> 32), m, 64);
  return ((unsigned long long)hi << 32) | lo;
}
static __device__ __forceinline__ double shfl_xor_f64(double v, int m) {
  return __longlong_as_double((long long)shfl_xor_u64((unsigned long long)__double_as_longlong(v), m));
}
static __device__ __forceinline__ void gl_lds16(const void* g, void* l) {
  __builtin_amdgcn_global_load_lds(
      (const __attribute__((address_space(1))) unsigned int*)g,
      (__attribute__((address_space(3))) unsigned int*)l, 16, 0, 0);
}

// ---------------------------------------------------------------------------
// transpose_keys: bf16-convert + transpose + ksq (global AND embedded in the
// record). Record (33KB, per 64-key chunk): [sub0 16KB: keys 0..31]
// [sub1 16KB: keys 32..63][ksq 64 floats][pad]. Each sub: [koct][key32][16B].
// knn_main staging is a LINEAR copy; A-frag reads conflict-free.
// ---------------------------------------------------------------------------
__global__ __launch_bounds__(256) void transpose_keys(const float* __restrict__ keys,
                                                      unsigned char* __restrict__ kbf,
                                                      float* __restrict__ ksq) {
  __shared__ __align__(16) unsigned char T[128 * 512];
  __shared__ float sq[128];
  const int t = threadIdx.x;
  const int lane = t & 63;
  const float4* src = (const float4*)(keys + (size_t)blockIdx.x * 128 * DDIM);
#pragma unroll
  for (int j = 0; j < 32; ++j) {
    int g = j * 256 + t;
    float4 v = src[g];
    int key = g >> 6;
    int u = lane >> 1, sub = lane & 1;
    unsigned lo = ((unsigned)f2bf(v.y) << 16) | f2bf(v.x);
    unsigned hi2 = ((unsigned)f2bf(v.w) << 16) | f2bf(v.z);
    unsigned long long p = ((unsigned long long)hi2 << 32) | lo;
    *(unsigned long long*)&T[key * 512 + ((u ^ (key & 7)) << 4) + (sub << 3)] = p;
    float ss = v.x * v.x + v.y * v.y + v.z * v.z + v.w * v.w;
#pragma unroll
    for (int off = 32; off; off >>= 1) ss += __shfl_xor(ss, off, 64);
    if (lane == 0) { ksq[blockIdx.x * 128 + key] = ss; sq[key] = ss; }
  }
  __syncthreads();
  // two 64-key chunk records per block
  unsigned char* rec0 = kbf + (size_t)(blockIdx.x * 2) * RECB;
#pragma unroll
  for (int j = 0; j < 16; ++j) {
    int ou = j * 256 + t;                 // sub(4) x koct(32) x key32(32)
    int sr = ou >> 10, rem = ou & 1023;
    int koct = rem >> 5, key32 = rem & 31;
    int keyl = sr * 32 + key32;           // 0..127
    unsigned char* dst = rec0 + (size_t)(sr >> 1) * RECB + (sr & 1) * 16384
                       + ((koct * 32 + key32) << 4);
    *(uint4*)dst = *(const uint4*)&T[keyl * 512 + ((koct ^ (keyl & 7)) << 4)];
  }
  if (t < 128) // embed ksq: chunk (t>>6), slot (t&63)
    *(float*)(rec0 + (size_t)(t >> 6) * RECB + 32768 + ((t & 63) << 2)) = sq[t];
}

// ---------------------------------------------------------------------------
// knn_main (32x32x16 operand-flipped + vmem-free COMPUTE + dual MFMA chains):
// 512 thr = 8 waves = 4 row-groups (ws, 32 rows) x 2 key-halves (mw, 32
// keys). A = keys (M=32, LDS), B = x rows (N=32, regs, pre-scaled by -2) ->
// C: col = x-row (lane&31), row = key ((reg&3)+8*(reg>>2)+4*(lane>>5)).
// Per chunk: 16 ds_read + 16 MFMA in TWO 8-deep chains (a0: s0..7, a1:
// s8..15, both init 0; summed in SEL) -> 2x MFMA ILP. ksq is read from the
// STAGED record via broadcast ds_read in SEL -> COMPUTE touches no vmem, so
// no hidden vmcnt drain; STAGE(c+1) stays in flight the whole period. The
// only vmem wait is entry vmcnt(0) on loads issued a full period earlier.
// Selection: tau filter + append; 8 streams/(row,split) = mw(2) x hi5(2) x
// chain-oct(2); tau_row = max of 8 running stream minima >= v8(split).
// Overflow (cnt>CAP) -> per-split exact rescan in refine (unconditional).
// ---------------------------------------------------------------------------
__global__ __launch_bounds__(512, 4) void knn_main(
    const float* __restrict__ x,
    const unsigned char* __restrict__ kbf,
    unsigned int* __restrict__ pools,
    unsigned int* __restrict__ counts,
    int CAP) {
  __shared__ __align__(16) unsigned char tiles[2][RECB]; // 66KB double buffer
  __shared__ float tauh[2][4][32];  // [mw][ws][col]; monotone, race-benign
  __shared__ unsigned int rowcnt[128];

  const int t = threadIdx.x;
  const int lane = t & 63;
  const int wv = t >> 6;          // 0..7
  const int mw = wv & 1;          // key half (32 keys)
  const int ws = wv >> 1;         // row group (32 rows)
  const int col = lane & 31;      // this lane's x-row within the group
  const int hi5 = lane >> 5;

  const int split = blockIdx.x & (NSPLIT - 1);
  const int rb = (blockIdx.x >> 4) * ROWS_PER_BLK;

  const int xrow = rb + ws * 32 + col;
  const int rl = ws * 32 + col;   // block-local row

  // ---- B fragments: one 32-row set, 16 K-slices, PRE-SCALED by -2 (64 VGPR)
  bf16x8 xb[16];
#pragma unroll
  for (int s = 0; s < 16; ++s) {
    const float* p = x + (size_t)xrow * DDIM + s * 16 + hi5 * 8;
    float4 a = *(const float4*)p, b = *(const float4*)(p + 4);
    union { unsigned short us[8]; bf16x8 v; } u;
    u.us[0]=f2bf(-2.f*a.x); u.us[1]=f2bf(-2.f*a.y); u.us[2]=f2bf(-2.f*a.z); u.us[3]=f2bf(-2.f*a.w);
    u.us[4]=f2bf(-2.f*b.x); u.us[5]=f2bf(-2.f*b.y); u.us[6]=f2bf(-2.f*b.z); u.us[7]=f2bf(-2.f*b.w);
    xb[s] = u.v;
  }

  if (t < 128) rowcnt[t] = 0;

  float sminA = FLT_MAX, sminB = FLT_MAX; // per-lane chain-oct stream minima
  const unsigned char* srcbase = kbf + (size_t)(split * NCHUNK) * RECB;
  const size_t pb = ((size_t)xrow * NSPLIT + split) * (size_t)CAP;

  auto STAGE = [&](int c, int buf) { // linear 32KB keys + 1KB ksq/pad
    const unsigned char* src = srcbase + (size_t)c * RECB;
#pragma unroll
    for (int i = 0; i < 4; ++i)
      gl_lds16(src + (((i * 512) + t) << 4),
               (unsigned char*)tiles[buf] + ((i * 512 + wv * 64) << 4));
    if (wv == 0)
      gl_lds16(src + 32768 + (lane << 4), (unsigned char*)tiles[buf] + 32768);
  };

  f32x16 a0, a1;

  auto COMPUTE = [&](int buf) { // pure LDS+MFMA; two independent 8-chains
    const unsigned char* rec = tiles[buf] + mw * 16384 + col * 16;
    a0 = 0.0f; a1 = 0.0f;
    __builtin_amdgcn_s_setprio(1);
#pragma unroll
    for (int s = 0; s < 8; ++s) {
      bf16x8 afA = *(const bf16x8*)(rec + (2 * s + hi5) * 512);
      bf16x8 afB = *(const bf16x8*)(rec + (2 * (s + 8) + hi5) * 512);
      a0 = __builtin_amdgcn_mfma_f32_32x32x16_bf16(afA, xb[s], a0, 0, 0, 0);
      a1 = __builtin_amdgcn_mfma_f32_32x32x16_bf16(afB, xb[s + 8], a1, 0, 0, 0);
    }
    __builtin_amdgcn_s_setprio(0);
  };

  auto SEL = [&](int c, int buf, bool append, float tau) {
    const float* sqp = (const float*)(tiles[buf] + 32768) + mw * 32 + hi5 * 4;
    float4 q0 = *(const float4*)(sqp);       // broadcast ds_reads (free)
    float4 q1 = *(const float4*)(sqp + 8);
    float4 q2 = *(const float4*)(sqp + 16);
    float4 q3 = *(const float4*)(sqp + 24);
    float sc[16];
#pragma unroll
    for (int i = 0; i < 4; ++i) {
      sc[i]      = a0[i]      + a1[i]      + ((const float*)&q0)[i];
      sc[4 + i]  = a0[4 + i]  + a1[4 + i]  + ((const float*)&q1)[i];
      sc[8 + i]  = a0[8 + i]  + a1[8 + i]  + ((const float*)&q2)[i];
      sc[12 + i] = a0[12 + i] + a1[12 + i] + ((const float*)&q3)[i];
    }
    float m0 = sc[0], m1 = sc[8];
#pragma unroll
    for (int r = 1; r < 8; ++r) { m0 = fminf(m0, sc[r]); m1 = fminf(m1, sc[8 + r]); }
    sminA = fminf(sminA, m0);
    sminB = fminf(sminB, m1);
    if (append && fminf(m0, m1) <= tau) { // rare
      const int kbase = c * CHUNK_KEYS + mw * 32 + 4 * hi5;
#pragma unroll
      for (int r = 0; r < 16; ++r) {
        if (sc[r] <= tau) {
          int key = kbase + (r & 3) + 8 * (r >> 2); // 12-bit local idx
          unsigned slot = atomicAdd(&rowcnt[rl], 1u);
          if ((int)slot < CAP)
            pools[pb + slot] = (ford(sc[r]) & 0xFFFFF000u) | (unsigned)key;
        }
      }
    }
  };

  auto PUBLISH = [&]() {
    float l = fmaxf(sminA, sminB);            // max of my 2 oct-minima
    l = fmaxf(l, __shfl_xor(l, 32, 64));      // + lane-half partner
    if (hi5 == 0) tauh[mw][ws][col] = l;
  };
  auto RDTAU = [&]() {
    return fmaxf(tauh[0][ws][col], tauh[1][ws][col]); // max of 8 stream minima
  };

  // ---- prologue: tau from chunks 0 and 32 (minima only)
  STAGE(0, 0);
  STAGE(32, 1);
  __syncthreads();                 // full drain (prologue only)
  COMPUTE(0);  SEL(0, 0, false, 0.f);
  COMPUTE(1);  SEL(32, 1, false, 0.f);
  PUBLISH();
  __syncthreads();                 // tauh visible; prologue reads done

  // main loop: chunk 0 still valid in buf 0; STAGE(c+1) issued right after
  // the barrier stays in flight the whole period (COMPUTE/SEL touch no vmem).
#pragma unroll 1
  for (int c = 0; c < NCHUNK; ++c) {
    asm volatile("s_waitcnt vmcnt(0)" ::: "memory"); // only old loads/stores
    __builtin_amdgcn_s_barrier();
    const int cs = (c + 1 < NCHUNK) ? c + 1 : 0;     // tail: dummy re-stage
    STAGE(cs, (c + 1) & 1);
    float tau = RDTAU();           // lagged/racy: always a valid upper bound
    COMPUTE(c & 1);
    SEL(c, c & 1, true, tau);
    if (c & 1) PUBLISH();
  }

  __syncthreads();
  if (t < 128) counts[(size_t)(rb + t) * NSPLIT + split] = rowcnt[t];
}

// ---------------------------------------------------------------------------
// knn_refine: per row (1 wave): scan the row's 16 pools (overflowed split ->
// exact fp32 rescan of THAT 4096-key split), tournament top-24 by quantized
// score, fp64-exact recompute, true top-8 (idx tiebreak), average values.
// ---------------------------------------------------------------------------
__global__ __launch_bounds__(64) void knn_refine(
    const float* __restrict__ x,
    const float* __restrict__ keys,
    const float* __restrict__ ksq,
    const float* __restrict__ values,
    const unsigned int* __restrict__ pools,
    const unsigned int* __restrict__ counts,
    int CAP,
    float* __restrict__ out) {
  __shared__ float4 xl[64];
  const int row = blockIdx.x;
  const int lane = threadIdx.x;

  xl[lane] = ((const float4*)(x + (size_t)row * DDIM))[lane];
  __syncthreads();

  unsigned long long h[8];
#pragma unroll
  for (int i = 0; i < 8; ++i) h[i] = ~0ULL;

  auto insert = [&](unsigned long long v) {
    if (v < h[7]) {
#pragma unroll
      for (int j = 7; j >= 1; --j) {
        unsigned long long a = h[j - 1];
        unsigned long long mx = a > v ? a : v;
        h[j] = (v < h[j]) ? mx : h[j];
      }
      h[0] = h[0] < v ? h[0] : v;
    }
  };

  for (int s = 0; s < NSPLIT; ++s) {
    unsigned cnt = counts[(size_t)row * NSPLIT + s];
    if ((int)cnt <= CAP) {
      const unsigned int* pp = pools + ((size_t)row * NSPLIT + s) * (size_t)CAP;
      for (int i = lane; i < (int)cnt; i += 64) {
        unsigned p = pp[i];
        unsigned gk = (unsigned)(s * SPLIT_KEYS) + (p & 0xFFFu);
        insert(((unsigned long long)(p & 0xFFFFF000u) << 16) | gk);
      }
    } else {
      // overflow fallback: exact fp32 rescan of this 4096-key split
      for (int kk = lane; kk < SPLIT_KEYS; kk += 64) {
        int gk = s * SPLIT_KEYS + kk;
        const float4* kr = (const float4*)(keys + (size_t)gk * DDIM);
        float acc = 0.f;
#pragma unroll 8
        for (int d = 0; d < 64; ++d) {
          float4 kv = kr[d], xv = xl[d];
          acc = fmaf(kv.x, xv.x, acc); acc = fmaf(kv.y, xv.y, acc);
          acc = fmaf(kv.z, xv.z, acc); acc = fmaf(kv.w, xv.w, acc);
        }
        float sc = fmaf(-2.0f, acc, ksq[gk]);
        insert(((unsigned long long)(ford(sc) & 0xFFFFF000u) << 16) | (unsigned)gk);
      }
    }
  }

  // ---- tournament: top-24 by quantized score (u64 unique: gk in low 16b)
  int myidx = 0;
#pragma unroll 1
  for (int r = 0; r < 24; ++r) {
    unsigned long long m = h[0];
#pragma unroll
    for (int off = 32; off; off >>= 1) {
      unsigned long long o = shfl_xor_u64(m, off);
      m = o < m ? o : m;
    }
    if (lane == r) myidx = (int)(m & 0xFFFFu);
    if (h[0] == m) {
#pragma unroll
      for (int i = 0; i < 7; ++i) h[i] = h[i + 1];
      h[7] = ~0ULL;
    }
  }

  // ---- exact fp64 distance for my candidate
  double dv = 1e300;
  if (lane < 24) {
    const float4* kr = (const float4*)(keys + (size_t)myidx * DDIM);
    double s = 0.0;
#pragma unroll 8
    for (int d = 0; d < 64; ++d) {
      float4 kv = kr[d], xv = xl[d];
      double d0 = (double)xv.x - (double)kv.x;
      double d1 = (double)xv.y - (double)kv.y;
      double d2 = (double)xv.z - (double)kv.z;
      double d3 = (double)xv.w - (double)kv.w;
      s += d0 * d0 + d1 * d1 + d2 * d2 + d3 * d3;
    }
    dv = s;
  }

  int di = myidx;
  int chosen[8];
#pragma unroll
  for (int r = 0; r < 8; ++r) {
    double m = dv; int mi = di;
#pragma unroll
    for (int off = 32; off; off >>= 1) {
      double om = shfl_xor_f64(m, off);
      int omi = __shfl_xor(mi, off, 64);
      if (om < m || (om == m && omi < mi)) { m = om; mi = omi; }
    }
    chosen[r] = mi;
    if (di == mi && dv < 1e300) dv = 1e300;
  }

  if (lane < NCH) {
    double a = 0.0;
#pragma unroll
    for (int r = 0; r < 8; ++r) a += (double)values[(size_t)chosen[r] * NCH + lane];
    out[row * NCH + lane] = (float)(a * 0.125);
  }
}

// ---------------------------------------------------------------------------
extern "C" void kernel_launch(void* const* d_in, const int* in_sizes, int n_in,
                              void* d_out, int out_size, void* d_ws, size_t ws_size,
                              hipStream_t stream) {
  (void)in_sizes; (void)n_in; (void)out_size;
  const float* x      = (const float*)d_in[0];
  const float* keys   = (const float*)d_in[1];
  const float* values = (const float*)d_in[2];
  float* out = (float*)d_out;

  char* ws = (char*)d_ws;
  unsigned char* kbf = (unsigned char*)ws;                  // 34.6 MB key records
  size_t kbf_bytes = (size_t)1024 * RECB;                   // 34603008
  float* ksq = (float*)(ws + kbf_bytes);                    // 256 KB
  unsigned int* counts = (unsigned int*)(ws + kbf_bytes + 262144); // 256 KB
  unsigned int* pools  = (unsigned int*)(ws + kbf_bytes + 262144 + 262144);

  size_t base = kbf_bytes + 262144 + 262144;
  size_t cap = (ws_size > base) ? (ws_size - base) / ((size_t)B_ROWS * NSPLIT * 4) : 56;
  if (cap < 56) cap = 56;      // pool ends <49.8 MB (< proven 50.6)
  if (cap > 512) cap = 512;
  int CAP = (int)cap;

  transpose_keys<<<N_KEYS / 128, 256, 0, stream>>>(keys, kbf, ksq);
  knn_main<<<(B_ROWS / ROWS_PER_BLK) * NSPLIT, 512, 0, stream>>>(
      x, kbf, pools, counts, CAP);
  knn_refine<<<B_ROWS, 64, 0, stream>>>(x, keys, ksq, values, pools, counts, CAP, out);
}

// Round 19
// 278.121 us; speedup vs baseline: 1.1936x; 1.1936x over previous
//
#include <hip/hip_runtime.h>
#include <stdint.h>
#include <float.h>

// x[4096,256] f32, keys[65536,256] f32, values[65536,10] f32, k=8 (hardcoded).
#define B_ROWS 4096
#define N_KEYS 65536
#define DDIM 256
#define NCH 10

#define NSPLIT 16
#define SPLIT_KEYS (N_KEYS / NSPLIT)       // 4096
#define ROWS_PER_BLK 128
#define CHUNK_KEYS 32
#define NCHUNK (SPLIT_KEYS / CHUNK_KEYS)   // 128

typedef float f32x4 __attribute__((ext_vector_type(4)));
typedef short bf16x8 __attribute__((ext_vector_type(8)));

static __device__ __forceinline__ unsigned short f2bf(float f) {
  unsigned u = __float_as_uint(f);
  return (unsigned short)((u + 0x7FFFu + ((u >> 16) & 1u)) >> 16);
}
static __device__ __forceinline__ unsigned ford(float f) {
  unsigned u = __float_as_uint(f);
  return u ^ ((unsigned)((int)u >> 31) | 0x80000000u);
}
static __device__ __forceinline__ unsigned long long shfl_xor_u64(unsigned long long v, int m) {
  unsigned lo = __shfl_xor((unsigned)v, m, 64);
  unsigned hi = __shfl_xor((unsigned)(v >> 32), m, 64);
  return ((unsigned long long)hi << 32) | lo;
}
static __device__ __forceinline__ double shfl_xor_f64(double v, int m) {
  return __longlong_as_double((long long)shfl_xor_u64((unsigned long long)__double_as_longlong(v), m));
}
static __device__ __forceinline__ void gl_lds16(const void* g, void* l) {
  __builtin_amdgcn_global_load_lds(
      (const __attribute__((address_space(1))) unsigned int*)g,
      (__attribute__((address_space(3))) unsigned int*)l, 16, 0, 0);
}

// ---------------------------------------------------------------------------
// transpose_keys: bf16-convert + transpose + fused ksq. Output: per 32-key
// record [koct 0..31][key 0..31][16B] (16KB): knn_main staging is a LINEAR
// copy; A-frag ds_read_b128s are 256B-contiguous per 16-lane phase.
// ---------------------------------------------------------------------------
__global__ __launch_bounds__(256) void transpose_keys(const float* __restrict__ keys,
                                                      unsigned char* __restrict__ kbf,
                                                      float* __restrict__ ksq) {
  __shared__ __align__(16) unsigned char T[128 * 512];
  const int t = threadIdx.x;
  const int lane = t & 63;
  const float4* src = (const float4*)(keys + (size_t)blockIdx.x * 128 * DDIM);
#pragma unroll
  for (int j = 0; j < 32; ++j) {
    int g = j * 256 + t;
    float4 v = src[g];
    int key = g >> 6;
    int u = lane >> 1, sub = lane & 1;
    unsigned lo = ((unsigned)f2bf(v.y) << 16) | f2bf(v.x);
    unsigned hi2 = ((unsigned)f2bf(v.w) << 16) | f2bf(v.z);
    unsigned long long p = ((unsigned long long)hi2 << 32) | lo;
    *(unsigned long long*)&T[key * 512 + ((u ^ (key & 7)) << 4) + (sub << 3)] = p;
    float ss = v.x * v.x + v.y * v.y + v.z * v.z + v.w * v.w;
#pragma unroll
    for (int off = 32; off; off >>= 1) ss += __shfl_xor(ss, off, 64);
    if (lane == 0) ksq[blockIdx.x * 128 + key] = ss;
  }
  __syncthreads();
  uint4* dst = (uint4*)kbf + (size_t)blockIdx.x * 4096; // 4 records of 1024 units
#pragma unroll
  for (int j = 0; j < 16; ++j) {
    int ou = j * 256 + t;                 // rec(4) x koct(32) x key32(32)
    int rec = ou >> 10, rem = ou & 1023;
    int koct = rem >> 5, key32 = rem & 31;
    int keyl = rec * 32 + key32;
    dst[ou] = *(const uint4*)&T[keyl * 512 + ((koct ^ (keyl & 7)) << 4)];
  }
}

// ---------------------------------------------------------------------------
// knn_main (r9 convoy + T3/T4 counted-vmcnt 4-buffer ring + 2x row amort.):
// 512 thr = 8 waves = 2 key-halves (mw, 16 keys) x 4 row-groups (ws, 32 rows
// = 2 reg sets, feed-2). Block: 128 rows x one 4096-key split in 128 chunks
// of 32 keys. 2 blocks/CU (VGPR-capped 16 waves/CU). 4-buffer LDS ring with
// lookahead-2: per chunk ONE raw s_barrier preceded by s_waitcnt vmcnt(4) —
// the next 2 chunks' staging loads stay IN FLIGHT across the barrier (never
// drains; pool atomics only make the wait conservative, never unsafe).
// Ring safety: STAGE(c+3) overwrites buf((c+3)&3)=buf((c-1)&3), last read in
// period c-1; any wave past period-c's barrier has executed its period-(c-1)
// MFMAs (which waited on those ds_reads), so no wave can still be reading it.
// ksq folded into MFMA C-init (x pre-scaled by -2): scores = accumulator.
// Selection: tau filter + append (8 streams/row = hi(4) x mw(2); tau_row =
// max of 8 stream minima >= true 8th-best; overflow -> per-split exact
// rescan in refine, correctness unconditional).
// ---------------------------------------------------------------------------
__global__ __launch_bounds__(512, 4) void knn_main(
    const float* __restrict__ x,
    const unsigned char* __restrict__ kbf,
    const float* __restrict__ ksqg,
    unsigned int* __restrict__ pools,
    unsigned int* __restrict__ counts,
    int CAP) {
  __shared__ __align__(16) unsigned char tiles[4][16384]; // 64KB ring
  __shared__ float tauh[2][4][16][2]; // [set][ws][lo4][mw]; monotone
  __shared__ unsigned int rowcnt[128];

  const int t = threadIdx.x;
  const int lane = t & 63;
  const int wv = t >> 6;          // 0..7
  const int mw = wv & 1;          // key half (16 keys)
  const int ws = wv >> 1;         // row group (32 rows)
  const int lo4 = lane & 15;
  const int hi = lane >> 4;

  const int split = blockIdx.x & (NSPLIT - 1);
  const int rb = (blockIdx.x >> 4) * ROWS_PER_BLK;
  const int sb = split * SPLIT_KEYS;

  const int xrow0 = rb + ws * 32 + lo4;
  const int xrow1 = xrow0 + 16;
  const int rl0 = ws * 32 + lo4, rl1 = rl0 + 16;

  // ---- x fragments PRE-SCALED by -2 (folds the -2 into the MFMA)
  bf16x8 xb0[8], xb1[8];
#pragma unroll
  for (int s = 0; s < 8; ++s) {
    const float* p0 = x + (size_t)xrow0 * DDIM + s * 32 + hi * 8;
    const float* p1 = x + (size_t)xrow1 * DDIM + s * 32 + hi * 8;
    float4 a = *(const float4*)p0, b = *(const float4*)(p0 + 4);
    float4 c = *(const float4*)p1, d = *(const float4*)(p1 + 4);
    union { unsigned short us[8]; bf16x8 v; } u0, u1;
    u0.us[0]=f2bf(-2.f*a.x); u0.us[1]=f2bf(-2.f*a.y); u0.us[2]=f2bf(-2.f*a.z); u0.us[3]=f2bf(-2.f*a.w);
    u0.us[4]=f2bf(-2.f*b.x); u0.us[5]=f2bf(-2.f*b.y); u0.us[6]=f2bf(-2.f*b.z); u0.us[7]=f2bf(-2.f*b.w);
    u1.us[0]=f2bf(-2.f*c.x); u1.us[1]=f2bf(-2.f*c.y); u1.us[2]=f2bf(-2.f*c.z); u1.us[3]=f2bf(-2.f*c.w);
    u1.us[4]=f2bf(-2.f*d.x); u1.us[5]=f2bf(-2.f*d.y); u1.us[6]=f2bf(-2.f*d.z); u1.us[7]=f2bf(-2.f*d.w);
    xb0[s] = u0.v; xb1[s] = u1.v;
  }

  if (t < 128) rowcnt[t] = 0;

  float smin0 = FLT_MAX, smin1 = FLT_MAX;
  const unsigned char* srcbase = kbf + ((size_t)(split * NCHUNK) << 14);
  const size_t pb0 = ((size_t)xrow0 * NSPLIT + split) * (size_t)CAP;
  const size_t pb1 = ((size_t)xrow1 * NSPLIT + split) * (size_t)CAP;

  auto STAGE = [&](int c, int buf) { // linear 16KB, 2 x 16B per thread
    const unsigned char* src = srcbase + ((size_t)c << 14);
#pragma unroll
    for (int i = 0; i < 2; ++i)
      gl_lds16(src + (((i * 512) + t) << 4),
               (unsigned char*)tiles[buf] + ((i * 512 + wv * 64) << 4));
  };
  auto LOADQ = [&](int c) {
    return *(const float4*)(ksqg + sb + c * CHUNK_KEYS + mw * 16 + hi * 4);
  };

  f32x4 a0, a1;
  float4 kqc, kqn;

  auto COMPUTE = [&](int buf) { // acc init = ksq (fold), then MFMA
    const unsigned char* tile = tiles[buf];
    f32x4 ini;
    ini[0] = kqc.x; ini[1] = kqc.y; ini[2] = kqc.z; ini[3] = kqc.w;
    a0 = ini; a1 = ini;
    __builtin_amdgcn_s_setprio(1);
#pragma unroll
    for (int s = 0; s < 8; ++s) {
      const unsigned char* rp = tile + (s * 4 + hi) * 512 + (mw * 16 + lo4) * 16;
      bf16x8 af = *(const bf16x8*)rp;
      a0 = __builtin_amdgcn_mfma_f32_16x16x32_bf16(af, xb0[s], a0, 0, 0, 0);
      a1 = __builtin_amdgcn_mfma_f32_16x16x32_bf16(af, xb1[s], a1, 0, 0, 0);
    }
    __builtin_amdgcn_s_setprio(0);
  };

  auto SEL = [&](int c, bool append, float tau0, float tau1) {
    float mb0 = fminf(fminf(a0[0], a0[1]), fminf(a0[2], a0[3]));
    float mb1 = fminf(fminf(a1[0], a1[1]), fminf(a1[2], a1[3]));
    smin0 = fminf(smin0, mb0);
    smin1 = fminf(smin1, mb1);
    if (append) {
      const int kloc = c * CHUNK_KEYS + mw * 16 + hi * 4; // 12-bit local idx
      if (mb0 <= tau0) { // rare
#pragma unroll
        for (int i = 0; i < 4; ++i) {
          if (a0[i] <= tau0) {
            unsigned slot = atomicAdd(&rowcnt[rl0], 1u);
            if ((int)slot < CAP)
              pools[pb0 + slot] = (ford(a0[i]) & 0xFFFFF000u) | (unsigned)(kloc + i);
          }
        }
      }
      if (mb1 <= tau1) {
#pragma unroll
        for (int i = 0; i < 4; ++i) {
          if (a1[i] <= tau1) {
            unsigned slot = atomicAdd(&rowcnt[rl1], 1u);
            if ((int)slot < CAP)
              pools[pb1 + slot] = (ford(a1[i]) & 0xFFFFF000u) | (unsigned)(kloc + i);
          }
        }
      }
    }
  };

  auto RDTAU = [&](float& tau0, float& tau1) { // max over both mw entries
    tau0 = fmaxf(tauh[0][ws][lo4][0], tauh[0][ws][lo4][1]);
    tau1 = fmaxf(tauh[1][ws][lo4][0], tauh[1][ws][lo4][1]);
  };

  auto PUBLISH = [&]() { // per wave: max over its 4 hi-stream minima
    float p0 = fmaxf(smin0, __shfl_xor(smin0, 16, 64));
    p0 = fmaxf(p0, __shfl_xor(p0, 32, 64));
    float p1 = fmaxf(smin1, __shfl_xor(smin1, 16, 64));
    p1 = fmaxf(p1, __shfl_xor(p1, 32, 64));
    if (hi == 0) {
      tauh[0][ws][lo4][mw] = p0;
      tauh[1][ws][lo4][mw] = p1;
    }
  };

  // ---- prologue: tau from chunks 0 and 64 (minima only), then prime ring
  STAGE(0, 0);
  STAGE(64, 1);
  __syncthreads();               // full drain (prologue only)
  kqc = LOADQ(0);
  COMPUTE(0); SEL(0, false, 0.f, 0.f);
  kqc = LOADQ(64);
  COMPUTE(1); SEL(64, false, 0.f, 0.f);
  PUBLISH();
  __syncthreads();               // tauh visible; prologue reads done
  STAGE(1, 1);                   // chunk 0 still valid in buf 0
  STAGE(2, 2);
  kqc = LOADQ(0);
  kqn = LOADQ(1);

#pragma unroll 1
  for (int c = 0; c < NCHUNK; ++c) {
    asm volatile("s_waitcnt vmcnt(4)" ::: "memory"); // chunk c landed; c+1,c+2 in flight
    __builtin_amdgcn_s_barrier();
    float tau0, tau1;
    RDTAU(tau0, tau1);           // lagged/racy tau: always a valid upper bound
    COMPUTE(c & 3);
    SEL(c, true, tau0, tau1);
    if (c & 1) PUBLISH();
    kqc = kqn;
    kqn = LOADQ((c + 2 < NCHUNK) ? c + 2 : 0);
    const int cs = (c + 3 < NCHUNK) ? c + 3 : c + 3 - NCHUNK; // wrap: dummy
    STAGE(cs, (c + 3) & 3);
  }

  __syncthreads();
  if (t < 128) counts[(size_t)(rb + t) * NSPLIT + split] = rowcnt[t];
}

// ---------------------------------------------------------------------------
// knn_refine: per row (1 wave): scan the row's 16 pools (overflowed split ->
// exact fp32 rescan of THAT 4096-key split), tournament top-24 by quantized
// score, fp64-exact recompute, true top-8 (idx tiebreak), average values.
// ---------------------------------------------------------------------------
__global__ __launch_bounds__(64) void knn_refine(
    const float* __restrict__ x,
    const float* __restrict__ keys,
    const float* __restrict__ ksq,
    const float* __restrict__ values,
    const unsigned int* __restrict__ pools,
    const unsigned int* __restrict__ counts,
    int CAP,
    float* __restrict__ out) {
  __shared__ float4 xl[64];
  const int row = blockIdx.x;
  const int lane = threadIdx.x;

  xl[lane] = ((const float4*)(x + (size_t)row * DDIM))[lane];
  __syncthreads();

  unsigned long long h[8];
#pragma unroll
  for (int i = 0; i < 8; ++i) h[i] = ~0ULL;

  auto insert = [&](unsigned long long v) {
    if (v < h[7]) {
#pragma unroll
      for (int j = 7; j >= 1; --j) {
        unsigned long long a = h[j - 1];
        unsigned long long mx = a > v ? a : v;
        h[j] = (v < h[j]) ? mx : h[j];
      }
      h[0] = h[0] < v ? h[0] : v;
    }
  };

  for (int s = 0; s < NSPLIT; ++s) {
    unsigned cnt = counts[(size_t)row * NSPLIT + s];
    if ((int)cnt <= CAP) {
      const unsigned int* pp = pools + ((size_t)row * NSPLIT + s) * (size_t)CAP;
      for (int i = lane; i < (int)cnt; i += 64) {
        unsigned p = pp[i];
        unsigned gk = (unsigned)(s * SPLIT_KEYS) + (p & 0xFFFu);
        insert(((unsigned long long)(p & 0xFFFFF000u) << 16) | gk);
      }
    } else {
      // overflow fallback: exact fp32 rescan of this 4096-key split
      for (int kk = lane; kk < SPLIT_KEYS; kk += 64) {
        int gk = s * SPLIT_KEYS + kk;
        const float4* kr = (const float4*)(keys + (size_t)gk * DDIM);
        float acc = 0.f;
#pragma unroll 8
        for (int d = 0; d < 64; ++d) {
          float4 kv = kr[d], xv = xl[d];
          acc = fmaf(kv.x, xv.x, acc); acc = fmaf(kv.y, xv.y, acc);
          acc = fmaf(kv.z, xv.z, acc); acc = fmaf(kv.w, xv.w, acc);
        }
        float sc = fmaf(-2.0f, acc, ksq[gk]);
        insert(((unsigned long long)(ford(sc) & 0xFFFFF000u) << 16) | (unsigned)gk);
      }
    }
  }

  // ---- tournament: top-24 by quantized score (u64 unique: gk in low 16b)
  int myidx = 0;
#pragma unroll 1
  for (int r = 0; r < 24; ++r) {
    unsigned long long m = h[0];
#pragma unroll
    for (int off = 32; off; off >>= 1) {
      unsigned long long o = shfl_xor_u64(m, off);
      m = o < m ? o : m;
    }
    if (lane == r) myidx = (int)(m & 0xFFFFu);
    if (h[0] == m) {
#pragma unroll
      for (int i = 0; i < 7; ++i) h[i] = h[i + 1];
      h[7] = ~0ULL;
    }
  }

  // ---- exact fp64 distance for my candidate
  double dv = 1e300;
  if (lane < 24) {
    const float4* kr = (const float4*)(keys + (size_t)myidx * DDIM);
    double s = 0.0;
#pragma unroll 8
    for (int d = 0; d < 64; ++d) {
      float4 kv = kr[d], xv = xl[d];
      double d0 = (double)xv.x - (double)kv.x;
      double d1 = (double)xv.y - (double)kv.y;
      double d2 = (double)xv.z - (double)kv.z;
      double d3 = (double)xv.w - (double)kv.w;
      s += d0 * d0 + d1 * d1 + d2 * d2 + d3 * d3;
    }
    dv = s;
  }

  int di = myidx;
  int chosen[8];
#pragma unroll
  for (int r = 0; r < 8; ++r) {
    double m = dv; int mi = di;
#pragma unroll
    for (int off = 32; off; off >>= 1) {
      double om = shfl_xor_f64(m, off);
      int omi = __shfl_xor(mi, off, 64);
      if (om < m || (om == m && omi < mi)) { m = om; mi = omi; }
    }
    chosen[r] = mi;
    if (di == mi && dv < 1e300) dv = 1e300;
  }

  if (lane < NCH) {
    double a = 0.0;
#pragma unroll
    for (int r = 0; r < 8; ++r) a += (double)values[(size_t)chosen[r] * NCH + lane];
    out[row * NCH + lane] = (float)(a * 0.125);
  }
}

// ---------------------------------------------------------------------------
extern "C" void kernel_launch(void* const* d_in, const int* in_sizes, int n_in,
                              void* d_out, int out_size, void* d_ws, size_t ws_size,
                              hipStream_t stream) {
  (void)in_sizes; (void)n_in; (void)out_size;
  const float* x      = (const float*)d_in[0];
  const float* keys   = (const float*)d_in[1];
  const float* values = (const float*)d_in[2];
  float* out = (float*)d_out;

  char* ws = (char*)d_ws;
  unsigned char* kbf = (unsigned char*)ws;                            // 32 MB transposed bf16 keys
  float* ksq   = (float*)(ws + 33554432);                             // 256 KB
  unsigned int* counts = (unsigned int*)(ws + 33554432 + 262144);     // 256 KB (4096x16)
  unsigned int* pools  = (unsigned int*)(ws + 33554432 + 262144 + 262144);

  size_t base = 33554432 + 262144 + 262144;
  size_t cap = (ws_size > base) ? (ws_size - base) / ((size_t)B_ROWS * NSPLIT * 4) : 60;
  if (cap < 60) cap = 60;      // 60 -> pool ends <49.8 MB (< proven 50.6)
  if (cap > 512) cap = 512;
  int CAP = (int)cap;

  transpose_keys<<<N_KEYS / 128, 256, 0, stream>>>(keys, kbf, ksq);
  knn_main<<<(B_ROWS / ROWS_PER_BLK) * NSPLIT, 512, 0, stream>>>(
      x, kbf, ksq, pools, counts, CAP);
  knn_refine<<<B_ROWS, 64, 0, stream>>>(x, keys, ksq, values, pools, counts, CAP, out);
}